// Round 9
// baseline (122.367 us; speedup 1.0000x reference)
//
#include <hip/hip_runtime.h>
#include <math.h>

#define LOG_2PI_F 1.8378770664093453f
#define EPS_F 1e-10f
#define NB 32        // batches
#define CV 512       // components per batch (C*V)
#define PPW 8        // points per wave
#define KPL 8        // comps per lane = CV / 64

// Wave-per-8-points, params in registers.
// Lane l holds comps c = l + 64*j (j=0..KPL-1) for the wave's batch.
// amdgpu_waves_per_eu(2,4): min 2 waves/EU (VGPR cap 256), max 4 -> the
// allocator must NOT spill to chase 8 waves/EU (round-7 failure: VGPR=64,
// 17.5 MB scratch writes).
__global__ __launch_bounds__(256)
__attribute__((amdgpu_waves_per_eu(2, 4)))
void capsule_main(
    const float* __restrict__ x,
    const float* __restrict__ vote,
    const float* __restrict__ scales,
    const float* __restrict__ log_pres,
    const int* __restrict__ batch,
    float* __restrict__ out_pe,
    int n_pts)
{
    const int tid  = threadIdx.x;
    const int lane = tid & 63;
    const int wave = blockIdx.x * (blockDim.x >> 6) + (tid >> 6);
    const int p0   = wave * PPW;
    if (p0 >= n_pts) return;

    // batch of point p0 + (lane&7); clamped for tail safety
    int pidx = p0 + (lane & 7);
    if (pidx >= n_pts) pidx = n_pts - 1;
    const int  pb8     = batch[pidx];
    const int  b0      = __builtin_amdgcn_readfirstlane(pb8);
    const bool uniform = (__ballot(pb8 == b0) == ~0ull);

    // packed per-comp params in registers: a* = mu_d * inv, inv, coef
    float a0[KPL], a1[KPL], a2[KPL], a3[KPL], a4[KPL], a5[KPL];
    float ainv[KPL], acoef[KPL];

    auto load_params = [&](int b) {
        #pragma unroll
        for (int j = 0; j < KPL; ++j) {
            const int c = b * CV + lane + 64 * j;   // coalesced across lanes
            float s   = fmaxf(scales[c], EPS_F);
            float inv = 1.0f / s;
            const float* mu = vote + (size_t)c * 6;
            a0[j] = mu[0] * inv;
            a1[j] = mu[1] * inv;
            a2[j] = mu[2] * inv;
            a3[j] = mu[3] * inv;
            a4[j] = mu[4] * inv;
            a5[j] = mu[5] * inv;
            ainv[j]  = inv;
            acoef[j] = log_pres[c] - 6.0f * __logf(s) - 3.0f * LOG_2PI_F;
        }
    };

    load_params(b0);

    float wavesum = 0.0f;
    int   cur_b   = b0;

    #pragma unroll
    for (int q = 0; q < PPW; ++q) {
        const int p = p0 + q;
        if (p >= n_pts) break;

        if (!uniform) {
            const int pb = batch[p];
            if (pb != cur_b) { load_params(pb); cur_b = pb; }
        }

        const float* xp = x + (size_t)p * 6;   // wave-uniform -> scalar loads
        const float x0 = xp[0], x1 = xp[1], x2 = xp[2],
                    x3 = xp[3], x4 = xp[4], x5 = xp[5];

        // 8 logits per lane
        float l[KPL];
        #pragma unroll
        for (int j = 0; j < KPL; ++j) {
            float z, acc;
            z = fmaf(x0, ainv[j], -a0[j]); acc = z * z;
            z = fmaf(x1, ainv[j], -a1[j]); acc = fmaf(z, z, acc);
            z = fmaf(x2, ainv[j], -a2[j]); acc = fmaf(z, z, acc);
            z = fmaf(x3, ainv[j], -a3[j]); acc = fmaf(z, z, acc);
            z = fmaf(x4, ainv[j], -a4[j]); acc = fmaf(z, z, acc);
            z = fmaf(x5, ainv[j], -a5[j]); acc = fmaf(z, z, acc);
            l[j] = fmaf(acc, -0.5f, acoef[j]);
        }

        // lane-local max over 8
        float lm = fmaxf(fmaxf(fmaxf(l[0], l[1]), fmaxf(l[2], l[3])),
                         fmaxf(fmaxf(l[4], l[5]), fmaxf(l[6], l[7])));
        // wave allreduce max (6 steps)
        #pragma unroll
        for (int off = 1; off <= 32; off <<= 1)
            lm = fmaxf(lm, __shfl_xor(lm, off, 64));

        // exp-sum with global max (no rescales)
        float e0 = __expf(l[0] - lm) + __expf(l[1] - lm);
        float e1 = __expf(l[2] - lm) + __expf(l[3] - lm);
        float e2 = __expf(l[4] - lm) + __expf(l[5] - lm);
        float e3 = __expf(l[6] - lm) + __expf(l[7] - lm);
        float es = (e0 + e1) + (e2 + e3);
        // wave allreduce sum (6 steps)
        #pragma unroll
        for (int off = 1; off <= 32; off <<= 1)
            es += __shfl_xor(es, off, 64);

        const float lp = lm + __logf(es);   // identical on all lanes

        if (uniform) {
            wavesum += lp;
        } else if (lane == 0) {
            atomicAdd(&out_pe[cur_b], lp);  // rare boundary wave
        }
    }

    if (uniform && lane == 0)
        atomicAdd(&out_pe[b0], wavesum);    // one atomic per wave
}

// d_out[0] = mean(d_out[1..32])
__global__ void final_kernel(float* __restrict__ d_out) {
    int t = threadIdx.x;
    float v = (t < NB) ? d_out[1 + t] : 0.0f;
#pragma unroll
    for (int off = 32; off >= 1; off >>= 1) v += __shfl_xor(v, off, 64);
    if (t == 0) d_out[0] = v * (1.0f / NB);
}

extern "C" void kernel_launch(void* const* d_in, const int* in_sizes, int n_in,
                              void* d_out, int out_size, void* d_ws, size_t ws_size,
                              hipStream_t stream) {
    const float* x        = (const float*)d_in[0];
    const float* vote     = (const float*)d_in[1];
    const float* scales   = (const float*)d_in[2];
    const float* log_pres = (const float*)d_in[3];
    const int*   batch    = (const int*)d_in[4];
    float* out = (float*)d_out;

    int n_pts = in_sizes[0] / 6;

    // out is re-poisoned to 0xAA before every timed call -> zero it (capture-legal)
    hipMemsetAsync(d_out, 0, (size_t)out_size * sizeof(float), stream);

    int n_waves  = (n_pts + PPW - 1) / PPW;
    int n_blocks = (n_waves + 3) / 4;        // 4 waves (256 threads) per block
    capsule_main<<<n_blocks, 256, 0, stream>>>(x, vote, scales, log_pres, batch,
                                               out + 1, n_pts);

    final_kernel<<<1, 64, 0, stream>>>(out);
}

// Round 10
// 93.026 us; speedup vs baseline: 1.3154x; 1.3154x over previous
//
#include <hip/hip_runtime.h>
#include <math.h>

#define LOG_2PI_F 1.8378770664093453f
#define EPS_F 1e-10f
#define NB 32        // batches
#define CV 512       // components per batch (C*V)
#define PPW 8        // points per wave
#define KPL 8        // comps per lane = CV / 64

// Wave-per-8-points, params in registers, NO contended atomics:
// each uniform wave stores its partial sum to ws[wave] (unique slot);
// only rare batch-boundary waves atomicAdd directly to out_pe.
__global__ __launch_bounds__(256)
__attribute__((amdgpu_waves_per_eu(2, 4)))
void capsule_main(
    const float* __restrict__ x,
    const float* __restrict__ vote,
    const float* __restrict__ scales,
    const float* __restrict__ log_pres,
    const int* __restrict__ batch,
    float* __restrict__ out_pe,
    float* __restrict__ wsum,
    int n_pts)
{
    const int tid  = threadIdx.x;
    const int lane = tid & 63;
    const int wave = blockIdx.x * (blockDim.x >> 6) + (tid >> 6);
    const int p0   = wave * PPW;
    if (p0 >= n_pts) return;

    // batch of point p0 + (lane&7); clamped for tail safety
    int pidx = p0 + (lane & 7);
    if (pidx >= n_pts) pidx = n_pts - 1;
    const int  pb8     = batch[pidx];
    const int  b0      = __builtin_amdgcn_readfirstlane(pb8);
    const bool uniform = (__ballot(pb8 == b0) == ~0ull);

    // packed per-comp params in registers: a* = mu_d * inv, inv, coef
    float a0[KPL], a1[KPL], a2[KPL], a3[KPL], a4[KPL], a5[KPL];
    float ainv[KPL], acoef[KPL];

    auto load_params = [&](int b) {
        #pragma unroll
        for (int j = 0; j < KPL; ++j) {
            const int c = b * CV + lane + 64 * j;   // coalesced across lanes
            float s   = fmaxf(scales[c], EPS_F);
            float inv = 1.0f / s;
            const float* mu = vote + (size_t)c * 6;
            a0[j] = mu[0] * inv;
            a1[j] = mu[1] * inv;
            a2[j] = mu[2] * inv;
            a3[j] = mu[3] * inv;
            a4[j] = mu[4] * inv;
            a5[j] = mu[5] * inv;
            ainv[j]  = inv;
            acoef[j] = log_pres[c] - 6.0f * __logf(s) - 3.0f * LOG_2PI_F;
        }
    };

    load_params(b0);

    // per-point LSE using current register params; lp valid on all lanes
    auto point_lse = [&](int p) -> float {
        const float* xp = x + (size_t)p * 6;
        const float x0 = xp[0], x1 = xp[1], x2 = xp[2],
                    x3 = xp[3], x4 = xp[4], x5 = xp[5];
        float l[KPL];
        #pragma unroll
        for (int j = 0; j < KPL; ++j) {
            float z, acc;
            z = fmaf(x0, ainv[j], -a0[j]); acc = z * z;
            z = fmaf(x1, ainv[j], -a1[j]); acc = fmaf(z, z, acc);
            z = fmaf(x2, ainv[j], -a2[j]); acc = fmaf(z, z, acc);
            z = fmaf(x3, ainv[j], -a3[j]); acc = fmaf(z, z, acc);
            z = fmaf(x4, ainv[j], -a4[j]); acc = fmaf(z, z, acc);
            z = fmaf(x5, ainv[j], -a5[j]); acc = fmaf(z, z, acc);
            l[j] = fmaf(acc, -0.5f, acoef[j]);
        }
        float lm = fmaxf(fmaxf(fmaxf(l[0], l[1]), fmaxf(l[2], l[3])),
                         fmaxf(fmaxf(l[4], l[5]), fmaxf(l[6], l[7])));
        #pragma unroll
        for (int off = 1; off <= 32; off <<= 1)
            lm = fmaxf(lm, __shfl_xor(lm, off, 64));
        float e0 = __expf(l[0] - lm) + __expf(l[1] - lm);
        float e1 = __expf(l[2] - lm) + __expf(l[3] - lm);
        float e2 = __expf(l[4] - lm) + __expf(l[5] - lm);
        float e3 = __expf(l[6] - lm) + __expf(l[7] - lm);
        float es = (e0 + e1) + (e2 + e3);
        #pragma unroll
        for (int off = 1; off <= 32; off <<= 1)
            es += __shfl_xor(es, off, 64);
        return lm + __logf(es);
    };

    if (uniform && p0 + PPW <= n_pts) {
        // hot path: full 8 points, one batch, clean unrolled loop
        float wavesum = 0.0f;
        #pragma unroll
        for (int q = 0; q < PPW; ++q)
            wavesum += point_lse(p0 + q);
        if (lane == 0) wsum[wave] = wavesum;   // unique slot, no RMW
    } else {
        // rare: batch-boundary or ragged-tail wave -> direct atomics
        if (lane == 0) wsum[wave] = 0.0f;
        int cur_b = b0;
        for (int q = 0; q < PPW; ++q) {
            const int p = p0 + q;
            if (p >= n_pts) break;
            const int pb = batch[p];
            if (pb != cur_b) { load_params(pb); cur_b = pb; }
            float lp = point_lse(p);
            if (lane == 0) atomicAdd(&out_pe[cur_b], lp);
        }
    }
}

// One block: reduce ws[] per batch, fold boundary atomics, write mean.
__global__ __launch_bounds__(1024) void final_kernel(
    const float* __restrict__ wsum,
    const int* __restrict__ batch,
    float* __restrict__ d_out,   // [0]=mean, [1..32]=per-example
    int n_waves, int n_pts)
{
    __shared__ float part[NB];
    const int t = threadIdx.x;
    if (t < NB) part[t] = 0.0f;
    __syncthreads();

    for (int w = t; w < n_waves; w += 1024) {
        float s = wsum[w];                       // 0 for boundary waves
        int   pi = w * PPW;
        if (pi >= n_pts) pi = n_pts - 1;
        atomicAdd(&part[batch[pi]], s);          // LDS atomic, 32 bins
    }
    __syncthreads();

    if (t < 64) {
        float v = 0.0f;
        if (t < NB) {
            v = d_out[1 + t] + part[t];          // fold boundary atomics
            d_out[1 + t] = v;
        }
        #pragma unroll
        for (int off = 32; off >= 1; off >>= 1) v += __shfl_xor(v, off, 64);
        if (t == 0) d_out[0] = v * (1.0f / NB);
    }
}

extern "C" void kernel_launch(void* const* d_in, const int* in_sizes, int n_in,
                              void* d_out, int out_size, void* d_ws, size_t ws_size,
                              hipStream_t stream) {
    const float* x        = (const float*)d_in[0];
    const float* vote     = (const float*)d_in[1];
    const float* scales   = (const float*)d_in[2];
    const float* log_pres = (const float*)d_in[3];
    const int*   batch    = (const int*)d_in[4];
    float* out = (float*)d_out;
    float* ws  = (float*)d_ws;

    int n_pts   = in_sizes[0] / 6;
    int n_waves = (n_pts + PPW - 1) / PPW;

    // out re-poisoned to 0xAA before every timed call -> zero it (capture-legal).
    // ws slots are all overwritten by capsule_main, no zeroing needed.
    hipMemsetAsync(d_out, 0, (size_t)out_size * sizeof(float), stream);

    int n_blocks = (n_waves + 3) / 4;        // 4 waves (256 threads) per block
    capsule_main<<<n_blocks, 256, 0, stream>>>(x, vote, scales, log_pres, batch,
                                               out + 1, ws, n_pts);

    final_kernel<<<1, 1024, 0, stream>>>(ws, batch, out, n_waves, n_pts);
}